// Round 10
// baseline (3169.223 us; speedup 1.0000x reference)
//
#include <hip/hip_runtime.h>
#include <math.h>

#define BATCH 128
#define SEQN  512
#define XF    128
#define HF    256
#define BC    16    // batch tile per block (per group)
#define HC    8     // h tile per block
#define TCH   8     // time-chunk for phase A
#define NBLK  256
#define NTHR  256
#define NGRP  8     // batch groups
#define GSZ   32    // blocks per group (h tiles)

// ---- LDS layout (word offsets), total 32992 words = 131968 B ----
#define OFF_WX   0        // W_x  [k=128][j=8][g=6]           (6144, persistent)
#define OFF_G    6144     // gates [t=8][g=6][b*8+j]          (6144)
#define OFF_XS   12288    // x stage, wave-striped             (16384)
#define OFF_H    28672    // per-wave h [4][1024]              (4096)
#define OFF_CM   32768    // cm [b*8+j]                        (128)
#define OFF_COEF 32896    // 12 coef vectors x 8               (96)
#define LDS_WORDS 32992
#define LDS_BYTES (LDS_WORDS * 4)

struct Params {
  const float* x;
  const float* t;
  const float* w_h[4];   // fg, ig, in, og   [H][H]
  const float* w_x[6];   // fg, ig, in, og, tg1, tg2  [H][X]
  const float* coef[12]; // fg_b, ig_b, in_b, og_b, og_w_t, tg1_w_t, tg1_b, tg2_w_t, tg2_b, fg_w_c, ig_w_c, og_w_cn
  unsigned long long* h_tag;  // ws: [2][B][H] u64 = (tag<<32 | float bits)
  float* out;
};

__device__ __forceinline__ float sigmoidf_(float v) { return 1.0f / (1.0f + __expf(-v)); }
// fast tanh: exact at saturation, ~1e-7 rel error in core range (r9-verified)
__device__ __forceinline__ float tanhf_(float x) {
  const float e = __expf(2.0f * x);
  return 1.0f - 2.0f / (e + 1.0f);
}

// in-wave lane exchange (BitMode ds_swizzle: xor<<10 | 0x1F)
__device__ __forceinline__ float swzx1(float v) { return __int_as_float(__builtin_amdgcn_ds_swizzle(__float_as_int(v), 0x041F)); }
__device__ __forceinline__ float swzx2(float v) { return __int_as_float(__builtin_amdgcn_ds_swizzle(__float_as_int(v), 0x081F)); }
__device__ __forceinline__ float swzx4(float v) { return __int_as_float(__builtin_amdgcn_ds_swizzle(__float_as_int(v), 0x101F)); }

// ---- tag-in-word sync: each h element is an 8B atom (step_tag<<32 | bits) --
// No flags, no fences, no barriers. Writer stores (tag=s | h_s) with one
// relaxed agent-scope 8B store (atomic: tag and value travel together).
// Reader polls its own consume-set until every tag == s-1; the observed
// values ARE the payload. Overwrite safety: wave bq writing tag s has
// observed tag s-1 from every peer wave bq => each finished step s-1 =>
// finished reading tag s-2 => the buf[s&1] slots (last tag s-2) are dead.
// Init: memset(0) = (tag 0 | 0.0f) = h_0. Monotone tags, no RMW anywhere.

__global__ __launch_bounds__(NTHR, 1) void timelstm_kernel(Params p) {
  extern __shared__ float sm[];
  const int tid = threadIdx.x;
  const int bid = blockIdx.x;
  const int gi = bid & 7;          // batch group (XCD-resident under round-robin)
  const int mi = bid >> 3;         // member = h tile
  const int b0 = gi * BC;
  const int h0 = mi * HC;

  const int lane = tid & 63;
  const int bq = tid >> 6;         // wave id = batch quad
  const int kh = lane & 7;         // split-K slice (in-wave reducible)
  const int j  = lane >> 3;        // h feature within tile
  const int cc = tid >> 3, rr = tid & 7;   // phase-A projection coords
  const int c4 = cc << 2;                  // bt base (wave-aligned: [32bq..))

  // ---- one-time: W_h -> REGISTERS (per-thread slice, reused all 512 steps)
  float wrs[4][32];
#pragma unroll
  for (int g = 0; g < 4; ++g)
#pragma unroll
    for (int q = 0; q < 8; ++q) {
      const float4 v = *(const float4*)&p.w_h[g][(size_t)(h0 + j) * HF + kh * 32 + q * 4];
      wrs[g][q * 4 + 0] = v.x; wrs[g][q * 4 + 1] = v.y;
      wrs[g][q * 4 + 2] = v.z; wrs[g][q * 4 + 3] = v.w;
    }
  // ---- one-time: W_x slab -> LDS ----
  for (int i = tid; i < 6 * 8 * 128; i += NTHR) {     // W_x: [k][j][g]
    int g = i >> 10, jj = (i >> 7) & 7, k = i & 127;
    sm[OFF_WX + k * 48 + jj * 6 + g] = p.w_x[g][(h0 + jj) * XF + k];
  }
  if (tid < 96) sm[OFF_COEF + tid] = p.coef[tid >> 3][h0 + (tid & 7)];
  if (tid < 128) sm[OFF_CM + tid] = 0.0f;             // cm[b*8+j] = 0
  __syncthreads();   // the ONLY barrier: WX/COEF/CM visible to all waves

  unsigned tstep = 1;

  for (int tc0 = 0; tc0 < SEQN; tc0 += TCH) {
    // ============ phase A (fully wave-private, barrier-free) ============
    // stage x: wave stripe bt in [32bq, 32bq+32), swizzled by ((k>>2)&7)<<2
    {
#pragma unroll
      for (int half = 0; half < 2; ++half) {
        float4 xr[8];
#pragma unroll
        for (int q = 0; q < 8; ++q) {
          const int it = half * 8 + q;
          const int bt = (bq << 5) + it * 2 + (lane >> 5);
          xr[q] = *(const float4*)&p.x[((size_t)(b0 + (bt >> 3)) * SEQN + (tc0 + (bt & 7))) * XF + (lane & 31) * 4];
        }
#pragma unroll
        for (int q = 0; q < 8; ++q) {
          const int it = half * 8 + q;
          const int bt = (bq << 5) + it * 2 + (lane >> 5);
          const int k0 = (lane & 31) * 4;
          const float xb[4] = {xr[q].x, xr[q].y, xr[q].z, xr[q].w};
#pragma unroll
          for (int u = 0; u < 4; ++u) {
            const int k = k0 + u;
            sm[OFF_XS + k * 128 + (bt ^ (((k >> 2) & 7) << 2))] = xb[u];
          }
        }
      }
    }
    // projections (thread covers its wave's own bt quad c4..c4+3)
    {
      float tvr[4];
#pragma unroll
      for (int u = 0; u < 4; ++u) {
        const int bt = c4 + u;
        tvr[u] = p.t[(size_t)(b0 + (bt >> 3)) * SEQN + tc0 + (bt & 7)];
      }
      float a0[4], a1[4], a2[4], a3[4], a4[4], a5[4];
#pragma unroll
      for (int u = 0; u < 4; ++u) { a0[u]=0.f; a1[u]=0.f; a2[u]=0.f; a3[u]=0.f; a4[u]=0.f; a5[u]=0.f; }
      const float* wxp = &sm[OFF_WX + rr * 6];
#pragma unroll 4
      for (int k = 0; k < XF; ++k) {
        const float4 xv = *(const float4*)&sm[OFF_XS + k * 128 + (c4 ^ (((k >> 2) & 7) << 2))];
        const float2 wA = *(const float2*)&wxp[k * 48 + 0];
        const float2 wB = *(const float2*)&wxp[k * 48 + 2];
        const float2 wC = *(const float2*)&wxp[k * 48 + 4];
        const float xs[4] = {xv.x, xv.y, xv.z, xv.w};
#pragma unroll
        for (int u = 0; u < 4; ++u) {
          a0[u] += wA.x * xs[u]; a1[u] += wA.y * xs[u];
          a2[u] += wB.x * xs[u]; a3[u] += wB.y * xs[u];
          a4[u] += wC.x * xs[u]; a5[u] += wC.y * xs[u];
        }
      }
      const float cfg  = sm[OFF_COEF + 0 * 8 + rr], cig  = sm[OFF_COEF + 1 * 8 + rr];
      const float cin  = sm[OFF_COEF + 2 * 8 + rr];
      const float cogb = sm[OFF_COEF + 3 * 8 + rr], cogwt = sm[OFF_COEF + 4 * 8 + rr];
      const float ct1w = sm[OFF_COEF + 5 * 8 + rr], ct1b = sm[OFF_COEF + 6 * 8 + rr];
      const float ct2w = sm[OFF_COEF + 7 * 8 + rr], ct2b = sm[OFF_COEF + 8 * 8 + rr];
#pragma unroll
      for (int u = 0; u < 4; ++u) {
        const int bt = c4 + u, b = bt >> 3, t = bt & 7;
        const float tv = tvr[u];
        float* gp = &sm[OFF_G + t * 768 + b * 8 + rr];   // [t][g][b*8+j]
        gp[0]   = a0[u] + cfg;
        gp[128] = a1[u] + cig;
        gp[256] = a2[u] + cin;
        gp[384] = a3[u] + cogwt * tv + cogb;
        gp[512] = sigmoidf_(a4[u] + tanhf_(ct1w * tv) + ct1b);
        gp[640] = sigmoidf_(a5[u] + tanhf_(ct2w * tv) + ct2b);
      }
    }

    // ============ phase B: 8 recurrent steps, ZERO barriers ============
    for (int tt = 0; tt < TCH; ++tt) {
      const unsigned target = tstep - 1;            // tag of h_{s-1}
      // poll+load fused: wave bq's consume set = its 4 rows x 256 cols of
      // buf[(s-1)&1]; 16 u64/lane, coalesced 512B per (u,q) instruction.
      const unsigned long long* hsrc =
          p.h_tag + (size_t)((tstep - 1) & 1) * BATCH * HF +
          (size_t)(b0 + (bq << 2)) * HF;
      unsigned long long v[16];
      while (true) {
#pragma unroll
        for (int u = 0; u < 4; ++u)
#pragma unroll
          for (int q = 0; q < 4; ++q)
            v[u * 4 + q] = __hip_atomic_load(&hsrc[(size_t)u * HF + q * 64 + lane],
                                             __ATOMIC_RELAXED, __HIP_MEMORY_SCOPE_AGENT);
        bool ok = true;
#pragma unroll
        for (int i = 0; i < 16; ++i) ok &= ((unsigned)(v[i] >> 32) == target);
        if (__all((int)ok)) break;
      }
      // values -> swizzled wave-private LDS: addr(k,bi)=(k*4 ^ ((k>>5)&7)<<2)+bi
#pragma unroll
      for (int q = 0; q < 4; ++q) {
        const int k = q * 64 + lane;
        float4 w;
        w.x = __uint_as_float((unsigned)v[0 * 4 + q]);
        w.y = __uint_as_float((unsigned)v[1 * 4 + q]);
        w.z = __uint_as_float((unsigned)v[2 * 4 + q]);
        w.w = __uint_as_float((unsigned)v[3 * 4 + q]);
        const int a = OFF_H + (bq << 10) + ((k * 4) ^ (((k >> 5) & 7) << 2));
        *(float4*)&sm[a] = w;
      }

      // matmul: thread (bq, j, kh): acc[bi][g] over k = kh*32..+31, W in regs
      float acc[4][4];
#pragma unroll
      for (int bi = 0; bi < 4; ++bi)
#pragma unroll
        for (int g = 0; g < 4; ++g) acc[bi][g] = 0.f;

      const int hbase = OFF_H + (bq << 10) + (kh << 7);   // + kh*128
      const int khx = kh << 2;
#pragma unroll
      for (int kk = 0; kk < 32; ++kk) {
        const int off = ((((kk & 7) << 2) ^ khx)) + ((kk >> 3) << 5);
        const float4 hv = *(const float4*)&sm[hbase + off];   // h[k][bq*4..+3]
        const float w0 = wrs[0][kk], w1 = wrs[1][kk], w2 = wrs[2][kk], w3 = wrs[3][kk];
        acc[0][0] += hv.x * w0; acc[0][1] += hv.x * w1; acc[0][2] += hv.x * w2; acc[0][3] += hv.x * w3;
        acc[1][0] += hv.y * w0; acc[1][1] += hv.y * w1; acc[1][2] += hv.y * w2; acc[1][3] += hv.y * w3;
        acc[2][0] += hv.z * w0; acc[2][1] += hv.z * w1; acc[2][2] += hv.z * w2; acc[2][3] += hv.z * w3;
        acc[3][0] += hv.w * w0; acc[3][1] += hv.w * w1; acc[3][2] += hv.w * w2; acc[3][3] += hv.w * w3;
      }

      // in-wave reduce-scatter over kh (3 rounds): lane ends with
      // pre[g] = full dot for b = bq*4 + (kh&3)   (kh>=4 duplicates kh-4)
      const int kb0 = kh & 1, kb1 = (kh >> 1) & 1;
      float s1[2][4];
#pragma unroll
      for (int pp = 0; pp < 2; ++pp)
#pragma unroll
        for (int g = 0; g < 4; ++g) {
          const float mine  = kb0 ? acc[2 * pp + 1][g] : acc[2 * pp][g];
          const float yours = kb0 ? acc[2 * pp][g]     : acc[2 * pp + 1][g];
          s1[pp][g] = mine + swzx1(yours);
        }
      float s2[4];
#pragma unroll
      for (int g = 0; g < 4; ++g) {
        const float mine  = kb1 ? s1[1][g] : s1[0][g];
        const float yours = kb1 ? s1[0][g] : s1[1][g];
        s2[g] = mine + swzx2(yours);
      }
      float pre[4];
#pragma unroll
      for (int g = 0; g < 4; ++g) pre[g] = s2[g] + swzx4(s2[g]);

      // gates (all 64 lanes; kh>=4 redundant with kh-4, only kh<4 stores)
      {
        const int bi = kh & 3;
        const int b  = (bq << 2) + bi;
        const int ib = b * 8 + j;
        const float cm = sm[OFF_CM + ib];
        const float* gt = &sm[OFF_G + tt * 768 + ib];
        const float fgx = gt[0],   igx = gt[128], inx = gt[256];
        const float ogx = gt[384], tm1 = gt[512], tm2 = gt[640];
        const float igv = sigmoidf_(sm[OFF_COEF + 10 * 8 + j] * cm + pre[1] + igx);
        const float fgv = sigmoidf_(sm[OFF_COEF + 9 * 8 + j] * cm + pre[0] + fgx);
        const float inn = tanhf_(pre[2] + inx);
        const float cbase = fgv * cm, cinn = igv * inn;
        const float cmh = cbase + cinn * tm1;
        const float cmn = cbase + cinn * tm2;
        const float ogv = sigmoidf_(sm[OFF_COEF + 11 * 8 + j] * cmh + pre[3] + ogx);
        const float hn  = ogv * tanhf_(cmh);
        if (kh < 4) {
          sm[OFF_CM + ib] = cmn;
          // publish (tag=tstep | h_s) as a single 8B atom into buf[tstep&1]
          const unsigned long long pv =
              ((unsigned long long)tstep << 32) | (unsigned long long)__float_as_uint(hn);
          __hip_atomic_store(&p.h_tag[(size_t)(tstep & 1) * BATCH * HF +
                                      (size_t)(b0 + b) * HF + h0 + j],
                             pv, __ATOMIC_RELAXED, __HIP_MEMORY_SCOPE_AGENT);
          if (tc0 + tt == SEQN - 1) {
            p.out[(size_t)(b0 + b) * HF + h0 + j] = hn;
            p.out[(size_t)BATCH * HF + (size_t)(b0 + b) * HF + h0 + j] = cmn;
          }
        }
      }
      ++tstep;
    }
  }
}

extern "C" void kernel_launch(void* const* d_in, const int* in_sizes, int n_in,
                              void* d_out, int out_size, void* d_ws, size_t ws_size,
                              hipStream_t stream) {
  (void)in_sizes; (void)n_in; (void)out_size; (void)ws_size;
  Params p;
  p.x = (const float*)d_in[0];
  p.t = (const float*)d_in[1];
  p.w_h[0] = (const float*)d_in[3];   // fg_w_h
  p.w_h[1] = (const float*)d_in[7];   // ig_w_h
  p.w_h[2] = (const float*)d_in[10];  // in_w_h
  p.w_h[3] = (const float*)d_in[14];  // og_w_h
  p.w_x[0] = (const float*)d_in[4];   // fg_w_x
  p.w_x[1] = (const float*)d_in[8];   // ig_w_x
  p.w_x[2] = (const float*)d_in[11];  // in_w_x
  p.w_x[3] = (const float*)d_in[15];  // og_w_x
  p.w_x[4] = (const float*)d_in[18];  // tg1_w_x
  p.w_x[5] = (const float*)d_in[21];  // tg2_w_x
  p.coef[0]  = (const float*)d_in[5];   // fg_b
  p.coef[1]  = (const float*)d_in[9];   // ig_b
  p.coef[2]  = (const float*)d_in[12];  // in_b
  p.coef[3]  = (const float*)d_in[16];  // og_b
  p.coef[4]  = (const float*)d_in[17];  // og_w_t
  p.coef[5]  = (const float*)d_in[19];  // tg1_w_t
  p.coef[6]  = (const float*)d_in[20];  // tg1_b
  p.coef[7]  = (const float*)d_in[22];  // tg2_w_t
  p.coef[8]  = (const float*)d_in[23];  // tg2_b
  p.coef[9]  = (const float*)d_in[2];   // fg_w_c
  p.coef[10] = (const float*)d_in[6];   // ig_w_c
  p.coef[11] = (const float*)d_in[13];  // og_w_cn
  p.h_tag = (unsigned long long*)d_ws;              // [2][B][H] u64 = 512 KiB
  p.out = (float*)d_out;

  // memset gives (tag=0 | 0.0f) everywhere: h_0 = 0 with valid initial tags
  (void)hipMemsetAsync(d_ws, 0, (size_t)2 * BATCH * HF * 8, stream);
  (void)hipFuncSetAttribute((const void*)timelstm_kernel,
                            hipFuncAttributeMaxDynamicSharedMemorySize, LDS_BYTES);
  timelstm_kernel<<<dim3(NBLK), dim3(NTHR), LDS_BYTES, stream>>>(p);
}

// Round 11
// 2574.030 us; speedup vs baseline: 1.2312x; 1.2312x over previous
//
#include <hip/hip_runtime.h>
#include <math.h>

#define BATCH 128
#define SEQN  512
#define XF    128
#define HF    256
#define BC    16    // batch tile per block (per group)
#define HC    8     // h tile per block
#define TCH   8     // time-chunk for phase A
#define NBLK  256
#define NTHR  256
#define NGRP  8     // batch groups
#define GSZ   32    // blocks per group (h tiles)

// ---- LDS layout (word offsets), total 29028 words = 116112 B ----
#define OFF_WX   0        // W_x  [k=128][j=8][g=6]           (6144, persistent)
#define OFF_G    6144     // gates [t=8][g=6][b*8+j]          (6144)
#define OFF_X    12288    // union: A: x [k=128][bt swz]      (16384)
                          //        B: per-wave h [4][1024]   (4096)
#define OFF_CM   28672    // cm [b*8+j]                        (128)
#define OFF_TV   28800    // t-values [b*8+t]                  (128)
#define OFF_COEF 28928    // 12 coef vectors x 8               (96)
#define OFF_GO   29024    // LDS "go" counter (leader block's waves 1-3)
#define LDS_WORDS 29028
#define LDS_BYTES (LDS_WORDS * 4)

struct Params {
  const float* x;
  const float* t;
  const float* w_h[4];   // fg, ig, in, og   [H][H]
  const float* w_x[6];   // fg, ig, in, og, tg1, tg2  [H][X]
  const float* coef[12]; // fg_b, ig_b, in_b, og_b, og_w_t, tg1_w_t, tg1_b, tg2_w_t, tg2_b, fg_w_c, ig_w_c, og_w_cn
  float* h_buf;          // ws: [2][B][H]  (batch-major: coalesced row reads)
  unsigned* flags;       // ws: [NGRP][GSZ][16] member flags + [NGRP][16] round words
  unsigned* round;       // = flags + NGRP*GSZ*16
  float* out;
};

__device__ __forceinline__ float sigmoidf_(float v) { return 1.0f / (1.0f + __expf(-v)); }
// fast tanh: exact at saturation, ~1e-7 rel error in core range (r9-verified)
__device__ __forceinline__ float tanhf_(float x) {
  const float e = __expf(2.0f * x);
  return 1.0f - 2.0f / (e + 1.0f);
}

// in-wave lane exchange (BitMode ds_swizzle: xor<<10 | 0x1F)
__device__ __forceinline__ float swzx1(float v) { return __int_as_float(__builtin_amdgcn_ds_swizzle(__float_as_int(v), 0x041F)); }
__device__ __forceinline__ float swzx2(float v) { return __int_as_float(__builtin_amdgcn_ds_swizzle(__float_as_int(v), 0x081F)); }
__device__ __forceinline__ float swzx4(float v) { return __int_as_float(__builtin_amdgcn_ds_swizzle(__float_as_int(v), 0x101F)); }
__device__ __forceinline__ float swzx8(float v) { return __int_as_float(__builtin_amdgcn_ds_swizzle(__float_as_int(v), 0x201F)); }

// ---- fence-free sync, 2-LEVEL TREE (anti-congestion) ----------------------
// Level 0 (release, r8-proven): __syncthreads() drains each wave's vmcnt(0)
// before s_barrier, so all the block's agent h-stores are at the coherence
// point before tid0's relaxed agent flag store.
// Level 1: ONLY the group leader (mi==0) polls the 32 member flags; on
// detection it publishes the group's round word (single line) and proceeds.
// The other 31 members poll that ONE shared line (same-address wave load =
// one request). Transitivity: round>=s => leader saw all member flags>=s =>
// every block finished step s-1 and its h stores are committed.
__device__ __forceinline__ void post_arrive(unsigned* flags, int gi, int mi, unsigned val) {
  __syncthreads();
  if (threadIdx.x == 0) {
    __hip_atomic_store(&flags[(gi * GSZ + mi) * 16], val,
                       __ATOMIC_RELAXED, __HIP_MEMORY_SCOPE_AGENT);
  }
}

__device__ __forceinline__ void wave_wait(float* sm, const unsigned* flags,
                                          unsigned* round, int gi, int mi,
                                          unsigned target) {
  const int tid = threadIdx.x;
  if (mi == 0) {                        // group leader: aggregate member flags
    unsigned* go = (unsigned*)&sm[OFF_GO];
    if (tid < 64) {
      const bool need = tid < GSZ;
      const unsigned* f = &flags[(gi * GSZ + (tid & (GSZ - 1))) * 16];
      while (true) {
        unsigned v = need ? __hip_atomic_load(f, __ATOMIC_RELAXED, __HIP_MEMORY_SCOPE_AGENT)
                          : target;
        if (__all((int)(v >= target))) break;
      }
      if (tid == 0) {
        __hip_atomic_store(&round[gi * 16], target,
                           __ATOMIC_RELAXED, __HIP_MEMORY_SCOPE_AGENT);   // publish
        __hip_atomic_store(go, target, __ATOMIC_RELAXED, __HIP_MEMORY_SCOPE_WORKGROUP);
      }
    } else {
      while (__hip_atomic_load(go, __ATOMIC_RELAXED, __HIP_MEMORY_SCOPE_WORKGROUP) < target) {}
    }
  } else {                              // member: poll the single round word
    const unsigned* r = &round[gi * 16];
    while (__hip_atomic_load(r, __ATOMIC_RELAXED, __HIP_MEMORY_SCOPE_AGENT) < target) {}
  }
  asm volatile("" ::: "memory");        // keep agent h-loads below the spin
}

__global__ __launch_bounds__(NTHR, 1) void timelstm_kernel(Params p) {
  extern __shared__ float sm[];
  const int tid = threadIdx.x;
  const int bid = blockIdx.x;
  const int gi = bid & 7;          // batch group (XCD-resident under round-robin)
  const int mi = bid >> 3;         // member = h tile
  const int b0 = gi * BC;
  const int h0 = mi * HC;

  const int lane = tid & 63;
  const int bq = tid >> 6;         // wave id = batch quad
  const int kh = lane & 7;         // split-K slice (in-wave reducible)
  const int j  = lane >> 3;        // h feature within tile

  // ---- one-time: W_h -> per-thread slice (reused all 512 steps)
  float wrs[4][32];
#pragma unroll
  for (int g = 0; g < 4; ++g)
#pragma unroll
    for (int q = 0; q < 8; ++q) {
      const float4 v = *(const float4*)&p.w_h[g][(size_t)(h0 + j) * HF + kh * 32 + q * 4];
      wrs[g][q * 4 + 0] = v.x; wrs[g][q * 4 + 1] = v.y;
      wrs[g][q * 4 + 2] = v.z; wrs[g][q * 4 + 3] = v.w;
    }
  // ---- one-time: W_x slab -> LDS ----
  for (int i = tid; i < 6 * 8 * 128; i += NTHR) {     // W_x: [k][j][g]
    int g = i >> 10, jj = (i >> 7) & 7, k = i & 127;
    sm[OFF_WX + k * 48 + jj * 6 + g] = p.w_x[g][(h0 + jj) * XF + k];
  }
  if (tid < 96) sm[OFF_COEF + tid] = p.coef[tid >> 3][h0 + (tid & 7)];
  if (tid < 128) sm[OFF_CM + tid] = 0.0f;             // cm[b*8+j] = 0
  if (tid == 0) *(unsigned*)&sm[OFF_GO] = 0u;
  // zero h_buf[0] rows b0..b0+15: member 0 of each group (contiguous, agent scope)
  if (mi == 0) {
    unsigned long long* hbu = (unsigned long long*)p.h_buf + (size_t)b0 * (HF / 2);
    for (int i = tid; i < BC * HF / 2; i += NTHR) {
      __hip_atomic_store(&hbu[i], 0ull, __ATOMIC_RELAXED, __HIP_MEMORY_SCOPE_AGENT);
    }
  }
  post_arrive(p.flags, gi, mi, 1u);   // barrier drains the zero-stores first
  unsigned tstep = 1;
  int cur = 0;

  for (int tc0 = 0; tc0 < SEQN; tc0 += TCH) {
    __syncthreads();   // all waves of this block past last chunk's LDS reads
    // ================= phase A: input projections for 8 steps ==========
    // x -> LDS [k=128][bt=128], bt swizzled by ((k>>2)&7)<<2
    {
#pragma unroll
      for (int half = 0; half < 2; ++half) {
        float4 xr[8];
#pragma unroll
        for (int it = 0; it < 8; ++it) {
          const int ri = (half * 8 + it) * 8 + (tid >> 5);   // row = b*8+t
          xr[it] = *(const float4*)&p.x[((size_t)(b0 + (ri >> 3)) * SEQN + (tc0 + (ri & 7))) * XF + (tid & 31) * 4];
        }
#pragma unroll
        for (int it = 0; it < 8; ++it) {
          const int ri = (half * 8 + it) * 8 + (tid >> 5);
          const int k0 = (tid & 31) * 4;
          const float xb[4] = {xr[it].x, xr[it].y, xr[it].z, xr[it].w};
#pragma unroll
          for (int u = 0; u < 4; ++u) {
            const int k = k0 + u;
            sm[OFF_X + k * 128 + (ri ^ (((k >> 2) & 7) << 2))] = xb[u];
          }
        }
      }
      if (tid < 128)   // TV[b*8+t]
        sm[OFF_TV + tid] = p.t[(size_t)(b0 + (tid >> 3)) * SEQN + tc0 + (tid & 7)];
    }
    __syncthreads();
    {
      // thread (c = col-tile of 4 bt, r = j): 6 gates x 4 cols, k = 0..127
      const int c = tid >> 3, r = tid & 7;
      const int c4 = c << 2;
      float a0[4], a1[4], a2[4], a3[4], a4[4], a5[4];
#pragma unroll
      for (int u = 0; u < 4; ++u) { a0[u]=0.f; a1[u]=0.f; a2[u]=0.f; a3[u]=0.f; a4[u]=0.f; a5[u]=0.f; }
      const float* wxp = &sm[OFF_WX + r * 6];
#pragma unroll 4
      for (int k = 0; k < XF; ++k) {
        const float4 xv = *(const float4*)&sm[OFF_X + k * 128 + (c4 ^ (((k >> 2) & 7) << 2))];
        const float2 wA = *(const float2*)&wxp[k * 48 + 0];
        const float2 wB = *(const float2*)&wxp[k * 48 + 2];
        const float2 wC = *(const float2*)&wxp[k * 48 + 4];
        const float xs[4] = {xv.x, xv.y, xv.z, xv.w};
#pragma unroll
        for (int u = 0; u < 4; ++u) {
          a0[u] += wA.x * xs[u]; a1[u] += wA.y * xs[u];
          a2[u] += wB.x * xs[u]; a3[u] += wB.y * xs[u];
          a4[u] += wC.x * xs[u]; a5[u] += wC.y * xs[u];
        }
      }
      const float cfg  = sm[OFF_COEF + 0 * 8 + r], cig  = sm[OFF_COEF + 1 * 8 + r];
      const float cin  = sm[OFF_COEF + 2 * 8 + r];
      const float cogb = sm[OFF_COEF + 3 * 8 + r], cogwt = sm[OFF_COEF + 4 * 8 + r];
      const float ct1w = sm[OFF_COEF + 5 * 8 + r], ct1b = sm[OFF_COEF + 6 * 8 + r];
      const float ct2w = sm[OFF_COEF + 7 * 8 + r], ct2b = sm[OFF_COEF + 8 * 8 + r];
#pragma unroll
      for (int u = 0; u < 4; ++u) {
        const int bt = c4 + u, b = bt >> 3, t = bt & 7;
        const float tv = sm[OFF_TV + bt];
        float* gp = &sm[OFF_G + t * 768 + b * 8 + r];   // [t][g][b*8+j]
        gp[0]   = a0[u] + cfg;
        gp[128] = a1[u] + cig;
        gp[256] = a2[u] + cin;
        gp[384] = a3[u] + cogwt * tv + cogb;
        gp[512] = sigmoidf_(a4[u] + tanhf_(ct1w * tv) + ct1b);
        gp[640] = sigmoidf_(a5[u] + tanhf_(ct2w * tv) + ct2b);
      }
    }
    __syncthreads();   // phase A done: OFF_X becomes per-wave h space below

    // ================= phase B: 8 recurrent steps, ONE barrier each =======
    for (int tt = 0; tt < TCH; ++tt) {
      wave_wait(sm, p.flags, p.round, gi, mi, tstep);
      // wave-private h stage, COALESCED: h_buf is [B][H]; wave bq reads its 4
      // rows (b0+bq*4..+3), each 1KB contiguous, transposed into the swizzled
      // wave-private region: addr(k,bi) = (k*4 ^ ((k>>5)&7)<<2) + bi.
      {
        const unsigned long long* hsrc = (const unsigned long long*)
            (p.h_buf + (size_t)cur * BATCH * HF + (size_t)(b0 + (bq << 2)) * HF);
        unsigned long long v[4][2];
#pragma unroll
        for (int u = 0; u < 4; ++u) {
          const unsigned long long* src = hsrc + (size_t)u * (HF / 2) + lane * 2;
          v[u][0] = __hip_atomic_load(src,     __ATOMIC_RELAXED, __HIP_MEMORY_SCOPE_AGENT);
          v[u][1] = __hip_atomic_load(src + 1, __ATOMIC_RELAXED, __HIP_MEMORY_SCOPE_AGENT);
        }
        float f[4][4];   // [row u][elem e]: h[b=bq*4+u][k=4*lane+e]
#pragma unroll
        for (int u = 0; u < 4; ++u) {
          union { unsigned long long u64; float2 f2; } x0, x1;
          x0.u64 = v[u][0]; x1.u64 = v[u][1];
          f[u][0] = x0.f2.x; f[u][1] = x0.f2.y; f[u][2] = x1.f2.x; f[u][3] = x1.f2.y;
        }
        const int swz = ((lane >> 3) & 7) << 2;
        const int wbase = OFF_X + (bq << 10);
#pragma unroll
        for (int e = 0; e < 4; ++e) {
          const int a = wbase + (((lane << 4) + (e << 2)) ^ swz);
          float2 lo = {f[0][e], f[1][e]};
          float2 hi = {f[2][e], f[3][e]};
          *(float2*)&sm[a]     = lo;   // bi = 0,1
          *(float2*)&sm[a + 2] = hi;   // bi = 2,3
        }
      }

      // matmul: thread (bq, j, kh): acc[bi][g] over k = kh*32..+31
      float acc[4][4];
#pragma unroll
      for (int bi = 0; bi < 4; ++bi)
#pragma unroll
        for (int g = 0; g < 4; ++g) acc[bi][g] = 0.f;

      const int hbase = OFF_X + (bq << 10) + (kh << 7);   // + kh*128
      const int khx = kh << 2;
#pragma unroll
      for (int kk = 0; kk < 32; ++kk) {
        const int off = ((((kk & 7) << 2) ^ khx)) + ((kk >> 3) << 5);
        const float4 hv = *(const float4*)&sm[hbase + off];   // h[k][bq*4..+3]
        const float w0 = wrs[0][kk], w1 = wrs[1][kk], w2 = wrs[2][kk], w3 = wrs[3][kk];
        acc[0][0] += hv.x * w0; acc[0][1] += hv.x * w1; acc[0][2] += hv.x * w2; acc[0][3] += hv.x * w3;
        acc[1][0] += hv.y * w0; acc[1][1] += hv.y * w1; acc[1][2] += hv.y * w2; acc[1][3] += hv.y * w3;
        acc[2][0] += hv.z * w0; acc[2][1] += hv.z * w1; acc[2][2] += hv.z * w2; acc[2][3] += hv.z * w3;
        acc[3][0] += hv.w * w0; acc[3][1] += hv.w * w1; acc[3][2] += hv.w * w2; acc[3][3] += hv.w * w3;
      }

      // in-wave reduce-scatter over kh (3 rounds): lane ends with
      // pre[g] = full dot for b = bq*4 + (kh&3)   (kh>=4 duplicates kh-4)
      const int kb0 = kh & 1, kb1 = (kh >> 1) & 1;
      float s1[2][4];
#pragma unroll
      for (int pp = 0; pp < 2; ++pp)
#pragma unroll
        for (int g = 0; g < 4; ++g) {
          const float mine  = kb0 ? acc[2 * pp + 1][g] : acc[2 * pp][g];
          const float yours = kb0 ? acc[2 * pp][g]     : acc[2 * pp + 1][g];
          s1[pp][g] = mine + swzx1(yours);
        }
      float s2[4];
#pragma unroll
      for (int g = 0; g < 4; ++g) {
        const float mine  = kb1 ? s1[1][g] : s1[0][g];
        const float yours = kb1 ? s1[0][g] : s1[1][g];
        s2[g] = mine + swzx2(yours);
      }
      float pre[4];
#pragma unroll
      for (int g = 0; g < 4; ++g) pre[g] = s2[g] + swzx4(s2[g]);

      // gates (all 64 lanes; kh>=4 redundant with kh-4, only kh<4 stores)
      {
        const int bi = kh & 3;
        const int b  = (bq << 2) + bi;
        const int ib = b * 8 + j;
        const float cm = sm[OFF_CM + ib];
        const float* gt = &sm[OFF_G + tt * 768 + ib];
        const float fgx = gt[0],   igx = gt[128], inx = gt[256];
        const float ogx = gt[384], tm1 = gt[512], tm2 = gt[640];
        const float igv = sigmoidf_(sm[OFF_COEF + 10 * 8 + j] * cm + pre[1] + igx);
        const float fgv = sigmoidf_(sm[OFF_COEF + 9 * 8 + j] * cm + pre[0] + fgx);
        const float inn = tanhf_(pre[2] + inx);
        const float cbase = fgv * cm, cinn = igv * inn;
        const float cmh = cbase + cinn * tm1;
        const float cmn = cbase + cinn * tm2;
        const float ogv = sigmoidf_(sm[OFF_COEF + 11 * 8 + j] * cmh + pre[3] + ogx);
        const float hn  = ogv * tanhf_(cmh);
        const float hn2 = swzx8(hn);                 // partner (j^1) value
        if (kh < 4) {
          sm[OFF_CM + ib] = cmn;
          if (!(j & 1)) {                            // paired 8B store: (j, j+1)
            union { float2 f; unsigned long long u; } cv;
            cv.f.x = hn; cv.f.y = hn2;
            unsigned long long* hdst =
                (unsigned long long*)(p.h_buf + (size_t)(cur ^ 1) * BATCH * HF +
                                      (size_t)(b0 + b) * HF + h0 + j);
            __hip_atomic_store(hdst, cv.u, __ATOMIC_RELAXED, __HIP_MEMORY_SCOPE_AGENT);
          }
          if (tc0 + tt == SEQN - 1) {
            p.out[(size_t)(b0 + b) * HF + h0 + j] = hn;
            p.out[(size_t)BATCH * HF + (size_t)(b0 + b) * HF + h0 + j] = cmn;
          }
        }
      }
      post_arrive(p.flags, gi, mi, tstep + 1);
      ++tstep;
      cur ^= 1;
    }
  }
}

extern "C" void kernel_launch(void* const* d_in, const int* in_sizes, int n_in,
                              void* d_out, int out_size, void* d_ws, size_t ws_size,
                              hipStream_t stream) {
  (void)in_sizes; (void)n_in; (void)out_size; (void)ws_size;
  Params p;
  p.x = (const float*)d_in[0];
  p.t = (const float*)d_in[1];
  p.w_h[0] = (const float*)d_in[3];   // fg_w_h
  p.w_h[1] = (const float*)d_in[7];   // ig_w_h
  p.w_h[2] = (const float*)d_in[10];  // in_w_h
  p.w_h[3] = (const float*)d_in[14];  // og_w_h
  p.w_x[0] = (const float*)d_in[4];   // fg_w_x
  p.w_x[1] = (const float*)d_in[8];   // ig_w_x
  p.w_x[2] = (const float*)d_in[11];  // in_w_x
  p.w_x[3] = (const float*)d_in[15];  // og_w_x
  p.w_x[4] = (const float*)d_in[18];  // tg1_w_x
  p.w_x[5] = (const float*)d_in[21];  // tg2_w_x
  p.coef[0]  = (const float*)d_in[5];   // fg_b
  p.coef[1]  = (const float*)d_in[9];   // ig_b
  p.coef[2]  = (const float*)d_in[12];  // in_b
  p.coef[3]  = (const float*)d_in[16];  // og_b
  p.coef[4]  = (const float*)d_in[17];  // og_w_t
  p.coef[5]  = (const float*)d_in[19];  // tg1_w_t
  p.coef[6]  = (const float*)d_in[20];  // tg1_b
  p.coef[7]  = (const float*)d_in[22];  // tg2_w_t
  p.coef[8]  = (const float*)d_in[23];  // tg2_b
  p.coef[9]  = (const float*)d_in[2];   // fg_w_c
  p.coef[10] = (const float*)d_in[6];   // ig_w_c
  p.coef[11] = (const float*)d_in[13];  // og_w_cn
  p.flags = (unsigned*)d_ws;                        // [8][32][16] u32 = 16 KiB
  p.round = p.flags + NGRP * GSZ * 16;              // [8][16] round words
  p.h_buf = (float*)((char*)d_ws + 32768);          // [2][B][H] f32 = 256 KiB
  p.out = (float*)d_out;

  (void)hipMemsetAsync(d_ws, 0, 32768, stream);  // member flags + round words = 0
  (void)hipFuncSetAttribute((const void*)timelstm_kernel,
                            hipFuncAttributeMaxDynamicSharedMemorySize, LDS_BYTES);
  timelstm_kernel<<<dim3(NBLK), dim3(NTHR), LDS_BYTES, stream>>>(p);
}